// Round 11
// baseline (223.008 us; speedup 1.0000x reference)
//
#include <hip/hip_runtime.h>
#include <math.h>

// ---------------- problem sizes ----------------
#define NB 4
#define LTOK 4096
#define DM 128
#define DI 256
#define NCH 256    // scan chunks
#define TCH 16     // steps per chunk
#define GSZ 16     // chunks per combine group
#define NG  16     // groups = NCH/GSZ

// ---------------- workspace layout (float offsets) ----------------
#define OFF_A2     0u          // A2 table [256d][16n] (4096)
#define OFF_BIAS2  73728u      // folded conv+bn bias [128]
#define OFF_YDSR   84096u      // bf16 gelu NCHW [4][128][64][64] (1048576 fl)
#define OFF_XPRE   2181248u    // bf16 xpre [4][4096][256] (2097152 fl)
#define OFF_S0     4278400u    // f32 S slices b=0,1 [2][256c][16n][256d] (2097152 fl)
#define OFF_Z      6375552u    // bf16 z [4][4096][256] (2097152 fl)
#define OFF_DELTA  10569856u   // bf16 delta [4][4096][256] (2097152 fl)
#define OFF_S1     12667008u   // f32 S slices b=2,3 (2097152 fl)
#define OFF_BC     14764160u   // f32 [4][4096][32]: 0-15 B, 16-31 C (524288)
#define OFF_DSUM   15288448u   // [4][256c][256d] (262144)
#define OFF_GS     15550592u   // [4][16g][16n][256d] group totals -> excl prefix (262144)
#define OFF_GD     15812736u   // [4][16g][256d] group dsum totals (16384)
#define OFF_XT     15829120u   // bf16: x-transpose (k0x/k12); then xinbf [4][4096][256]
#define OFF_WBF    17926272u   // bf16 conv weights*bn_inv [128co][9tap][64ci] (36864)
#define OFF_WCMP   17963136u   // bf16 composed xproj weights [320n][256k] (40960)
#define OFF_DPREF  18004096u   // f32 exclusive dsum prefix [4][256c][256d] (262144)
#define OFF_INWBF  19052672u   // bf16 in_w [512e][128k] (32768)
#define OFF_OUTWBF 19085440u   // bf16 out_w [128cc][256e] (16384)
// total 19101824 floats = 76.4 MB

#define DEV __device__ __forceinline__
#define L2E 1.4426950408889634f

typedef short bh8 __attribute__((ext_vector_type(8)));   // 8 bf16 (4 VGPR)
typedef float f4v __attribute__((ext_vector_type(4)));

DEV float fast_silu(float v) {
  return v * __builtin_amdgcn_rcpf(1.f + __expf(-v));
}

DEV unsigned short f2bf(float f) {                       // round-to-nearest-even
  unsigned int u = __float_as_uint(f);
  u = (u + 0x7FFFu + ((u >> 16) & 1u)) >> 16;
  return (unsigned short)u;
}

DEV float bf2f(unsigned short us) {
  return __uint_as_float((unsigned int)us << 16);
}

// =============== K0x: weight prep + x transpose (merged) ===============
__global__ __launch_bounds__(256) void k0x_prep(
    const float* __restrict__ conv_w, const float* __restrict__ conv_b,
    const float* __restrict__ bn_g, const float* __restrict__ bn_b,
    const float* __restrict__ bn_mean, const float* __restrict__ bn_var,
    const float* __restrict__ xproj_w, const float* __restrict__ A_log,
    const float* __restrict__ dtw, const float* __restrict__ in_w,
    const float* __restrict__ out_w, const float* __restrict__ x,
    float* __restrict__ ws) {
  __shared__ float t[64][65];
  if (blockIdx.x >= 1009) {
    // ---- transpose part: x [4][64][128][128] f32 -> xt [4][128][128][64] bf16
    const int bid = blockIdx.x - 1009;
    unsigned short* xt = (unsigned short*)(ws + OFF_XT);
    const int tid = threadIdx.x;
    const int ixh = bid & 1;
    const int iy = (bid >> 1) & 127;
    const int b = bid >> 8;
    {
      const int ixl = tid & 63, cw = tid >> 6;
#pragma unroll 4
      for (int i = 0; i < 16; ++i) {
        int ci = cw * 16 + i;
        t[ci][ixl] = x[(((size_t)(b * 64 + ci) * 128) + iy) * 128 + ixh * 64 + ixl];
      }
    }
    __syncthreads();
    {
      const int cil = tid & 63, iw = tid >> 6;
      unsigned short* dst = xt + (((size_t)(b * 128 + iy) * 128) + ixh * 64) * 64;
#pragma unroll 4
      for (int i = 0; i < 16; ++i) {
        int ix = iw * 16 + i;
        dst[ix * 64 + cil] = f2bf(t[cil][ix]);
      }
    }
    return;
  }
  // ---- prep part ----
  int i = blockIdx.x * 256 + threadIdx.x;
  if (i < 73728) {
    int ci = i & 63; int tap = (i >> 6) % 9; int co = i / 576;
    float inv = bn_g[co] * rsqrtf(bn_var[co] + 1e-5f);
    ((unsigned short*)(ws + OFF_WBF))[i] = f2bf(conv_w[co * 576 + ci * 9 + tap] * inv);
  } else if (i < 73856) {
    int co = i - 73728;
    float inv = bn_g[co] * rsqrtf(bn_var[co] + 1e-5f);
    ws[OFF_BIAS2 + co] = (conv_b[co] - bn_mean[co]) * inv + bn_b[co];
  } else if (i < 77952) {
    int j = i - 73856;
    ws[OFF_A2 + j] = -__expf(A_log[j]) * L2E;
  } else if (i < 159872) {
    // wcomp[n][k], n in [0,320)
    int j = i - 77952;
    int n = j >> 8, k = j & 255;
    float v = 0.f;
    if (n < 256) {
#pragma unroll
      for (int r = 0; r < 8; ++r)
        v = fmaf(dtw[n * 8 + r], xproj_w[r * 256 + k], v);
    } else if (n < 288) {
      v = xproj_w[(8 + n - 256) * 256 + k];
    }
    ((unsigned short*)(ws + OFF_WCMP))[j] = f2bf(v);
  } else if (i < 225408) {
    int j = i - 159872;                                  // [512e][128k]
    ((unsigned short*)(ws + OFF_INWBF))[j] = f2bf(in_w[j]);
  } else if (i < 258176) {
    int j = i - 225408;                                  // [128cc][256e]
    ((unsigned short*)(ws + OFF_OUTWBF))[j] = f2bf(out_w[j]);
  }
}

// =============== K12: conv3x3 s2 + BN + GELU + in_proj (fused) ===============
// R11: token-split -- block = (b, oy, token-half of 32). Grid 512 = 2
// blocks/CU (was 1), doubling the occupancy cap. Identical arithmetic.
__global__ __launch_bounds__(512) void k12_conv_inproj(
    const unsigned short* __restrict__ xt, const unsigned short* __restrict__ wbf,
    const float* __restrict__ bias2, const unsigned short* __restrict__ inwbf,
    unsigned short* __restrict__ ydsr, unsigned short* __restrict__ xpre,
    unsigned short* __restrict__ z) {
  __shared__ unsigned short ldt[32][136];
  const int tid = threadIdx.x;
  const int lane = tid & 63;
  const int w = tid >> 6;                 // 0..7
  const int col = lane & 15, quad = lane >> 4;
  const int half = blockIdx.x & 1;
  const int oy = (blockIdx.x >> 1) & 63;
  const int b = blockIdx.x >> 7;
  const int co_w = w * 16;
  const int iy0 = 2 * oy - 1;
  const int tokb = half * 32;
  const bh8 bzero = {};

  // ---- conv phase: 128 co x 32 tokens ----
  f4v acc[2];
#pragma unroll
  for (int nt = 0; nt < 2; ++nt) acc[nt] = (f4v){0.f, 0.f, 0.f, 0.f};
  const unsigned short* ap = wbf + (size_t)(co_w + col) * 576;
  for (int tap = 0; tap < 9; ++tap) {
    const int kh = tap / 3, kw = tap - kh * 3;
    const int iy = iy0 + kh;
    const unsigned short* xrow = xt + (long)(b * 128 + iy) * 8192;
    const bool oky = (iy >= 0);
#pragma unroll
    for (int kc = 0; kc < 2; ++kc) {
      const int cib = kc * 32 + quad * 8;
      bh8 a0 = *(const bh8*)&ap[tap * 64 + cib];
#pragma unroll
      for (int nt = 0; nt < 2; ++nt) {
        const int ix = 2 * (tokb + nt * 16 + col) - 1 + kw;
        bh8 bv = *(const bh8*)&xrow[(long)ix * 64 + cib];
        if (!(oky && ix >= 0)) bv = bzero;
        acc[nt] = __builtin_amdgcn_mfma_f32_16x16x32_bf16(a0, bv, acc[nt], 0, 0, 0);
      }
    }
  }
#pragma unroll
  for (int nt = 0; nt < 2; ++nt) {
    const int tl = nt * 16 + col;          // token local 0..31
    const int swz = (tl & 15) << 3;
#pragma unroll
    for (int r = 0; r < 4; ++r) {
      const int co = co_w + quad * 4 + r;
      float v = acc[nt][r] + bias2[co];
      float g = 0.5f * v * (1.f + erff(v * 0.70710678118f));
      unsigned short gb = f2bf(g);
      ydsr[(((size_t)(b * 128 + co) * 64) + oy) * 64 + tokb + tl] = gb;
      ldt[tl][co ^ swz] = gb;
    }
  }
  __syncthreads();

  // ---- in_proj phase: u[32t][128k] (LDS) x in_w[512e][128k] ----
  const size_t tglob0 = (size_t)(b * 4096 + oy * 64 + tokb);
#pragma unroll
  for (int tt = 0; tt < 2; ++tt) {
    const int row = tt * 16 + col;
    const int swz = (row & 15) << 3;
    bh8 afrag[4];
#pragma unroll
    for (int kb = 0; kb < 4; ++kb)
      afrag[kb] = *(const bh8*)&ldt[row][(quad * 8 + kb * 32) ^ swz];
    f4v acc2[4];
#pragma unroll
    for (int j = 0; j < 4; ++j) acc2[j] = (f4v){0.f, 0.f, 0.f, 0.f};
#pragma unroll
    for (int kb = 0; kb < 4; ++kb) {
#pragma unroll
      for (int j = 0; j < 4; ++j) {
        const int e_row = (w * 4 + j) * 16 + col;
        bh8 bfrag = *(const bh8*)&inwbf[(size_t)e_row * 128 + quad * 8 + kb * 32];
        acc2[j] = __builtin_amdgcn_mfma_f32_16x16x32_bf16(afrag[kb], bfrag, acc2[j], 0, 0, 0);
      }
    }
#pragma unroll
    for (int j = 0; j < 4; ++j) {
      const int e = (w * 4 + j) * 16 + col;
#pragma unroll
      for (int r = 0; r < 4; ++r) {
        const size_t t = tglob0 + tt * 16 + quad * 4 + r;
        if (e < 256) xpre[t * 256 + e] = f2bf(acc2[j][r]);
        else z[t * 256 + e - 256] = f2bf(acc2[j][r]);
      }
    }
  }
}

// =============== K45: conv1d+SiLU + composed proj MFMA + chunk-local scan ===============
// (R9 proven version: single chunk, wide uint4 IO.)
__global__ __launch_bounds__(256) void k45_mfma(
    const unsigned short* __restrict__ wcomp, const float* __restrict__ dtb,
    const unsigned short* __restrict__ xpre, const float* __restrict__ cw1,
    const float* __restrict__ cb1, const float* __restrict__ a2tab,
    unsigned short* __restrict__ xinbf, unsigned short* __restrict__ delta,
    float* __restrict__ bc, float* __restrict__ dsum,
    float* __restrict__ S0, float* __restrict__ S1) {
  __shared__ __align__(16) unsigned short sxp[19][264];
  __shared__ __align__(16) unsigned short ld_xin[16][264];
  __shared__ __align__(16) unsigned short ld_delta[16][264];
  __shared__ float ld_bc[16][33];
  const int tid = threadIdx.x;
  const int lane = tid & 63;
  const int w = tid >> 6;
  const int col = lane & 15, quad = lane >> 4;
  const int tt = blockIdx.x & 255, b = blockIdx.x >> 8;
  const int t0 = tt * 16;

  // ---- stage xpre rows t0-3 .. t0+15 into LDS (19 x 32 = 608 uint4) ----
  if (tt > 0) {
    const uint4* gsrc = (const uint4*)(xpre + ((size_t)(b * 4096 + t0 - 3)) * 256);
#pragma unroll
    for (int k = 0; k < 2; ++k) {
      const int idx = k * 256 + tid;
      *(uint4*)&sxp[idx >> 5][(idx & 31) * 8] = gsrc[idx];
    }
    {
      const int idx = 512 + tid;
      if (tid < 96) *(uint4*)&sxp[idx >> 5][(idx & 31) * 8] = gsrc[idx];
    }
  } else {
    // first chunk: rows 0..2 (tokens -3..-1) are zero
    const uint4* gsrc = (const uint4*)(xpre + ((size_t)(b * 4096)) * 256);
#pragma unroll
    for (int k = 0; k < 2; ++k) {
      const int idx = k * 256 + tid;
      const int row = idx >> 5;
      uint4 v = make_uint4(0u, 0u, 0u, 0u);
      if (row >= 3) v = gsrc[idx - 96];
      *(uint4*)&sxp[row][(idx & 31) * 8] = v;
    }
    {
      const int idx = 512 + tid;                 // rows 16..18, always >= 3
      if (tid < 96) *(uint4*)&sxp[idx >> 5][(idx & 31) * 8] = gsrc[idx - 96];
    }
  }
  __syncthreads();

  // ---- phase 1: conv1d + silu from LDS (thread = d) ----
  {
    const int d = tid;
    float4 w4 = *(const float4*)&cw1[d * 4];
    float bias = cb1[d];
    float xw[19];
#pragma unroll
    for (int i = 0; i < 19; ++i) xw[i] = bf2f(sxp[i][d]);
#pragma unroll
    for (int i = 0; i < 16; ++i) {
      float o = bias + w4.x * xw[i] + w4.y * xw[i + 1] + w4.z * xw[i + 2] +
                w4.w * xw[i + 3];
      ld_xin[i][d] = f2bf(fast_silu(o));
    }
  }
  __syncthreads();

  // ---- xinbf out via uint4 (2/thread), overlaps MFMA issue ----
  {
    uint4* gdst = (uint4*)(xinbf + ((size_t)(b * 4096 + t0)) * 256);
#pragma unroll
    for (int k = 0; k < 2; ++k) {
      const int idx = k * 256 + tid;
      gdst[idx] = *(const uint4*)&ld_xin[idx >> 5][(idx & 31) * 8];
    }
  }

  // ---- phase 2: MFMA ----
  {
    bh8 afrag[8];
#pragma unroll
    for (int kb = 0; kb < 8; ++kb)
      afrag[kb] = *(const bh8*)&ld_xin[col][quad * 8 + kb * 32];
    f4v acc[5];
#pragma unroll
    for (int j = 0; j < 5; ++j) acc[j] = (f4v){0.f, 0.f, 0.f, 0.f};

    const int nt0 = w * 5;
    const unsigned short* wb = wcomp + (size_t)(nt0 * 16 + col) * 256 + quad * 8;
#pragma unroll
    for (int kb = 0; kb < 8; ++kb) {
#pragma unroll
      for (int j = 0; j < 5; ++j) {
        bh8 bfrag = *(const bh8*)&wb[(size_t)j * 4096 + kb * 32];
        acc[j] = __builtin_amdgcn_mfma_f32_16x16x32_bf16(afrag[kb], bfrag, acc[j], 0, 0, 0);
      }
    }
#pragma unroll
    for (int j = 0; j < 5; ++j) {
      const int n = (nt0 + j) * 16 + col;
      if (n < 256) {
        float bias = dtb[n];
#pragma unroll
        for (int r = 0; r < 4; ++r) {
          float s = acc[j][r] + bias;
          float dl = fmaxf(s, 0.f) + __logf(1.f + __expf(-fabsf(s)));  // softplus
          ld_delta[quad * 4 + r][n] = f2bf(dl);
        }
      } else if (n < 288) {
#pragma unroll
        for (int r = 0; r < 4; ++r) ld_bc[quad * 4 + r][n - 256] = acc[j][r];
      }
    }
  }
  __syncthreads();

  // ---- phase 3: chunk-local scan from LDS (thread = d) ----
  {
    const int d = tid;
    float A2[16];
#pragma unroll
    for (int j = 0; j < 4; ++j) {
      float4 a = *(const float4*)&a2tab[d * 16 + j * 4];
      A2[4 * j + 0] = a.x; A2[4 * j + 1] = a.y;
      A2[4 * j + 2] = a.z; A2[4 * j + 3] = a.w;
    }
    float h[16];
#pragma unroll
    for (int n = 0; n < 16; ++n) h[n] = 0.f;
    float ds = 0.f;
#pragma unroll 4
    for (int i = 0; i < TCH; ++i) {
      float dl = bf2f(ld_delta[i][d]);
      float xv = bf2f(ld_xin[i][d]);
      ds += dl;
      float dlx = dl * xv;
#pragma unroll
      for (int n = 0; n < 16; ++n)
        h[n] = fmaf(exp2f(dl * A2[n]), h[n], dlx * ld_bc[i][n]);
    }
    dsum[((size_t)b * NCH + tt) * 256 + d] = ds;
    float* S = (b & 2) ? (S1 + (size_t)(b & 1) * 1048576)
                       : (S0 + (size_t)(b & 1) * 1048576);
    const size_t sbase = ((size_t)tt * 16) * 256 + d;
#pragma unroll
    for (int n = 0; n < 16; ++n) S[sbase + (size_t)n * 256] = h[n];
  }

  // ---- delta out via uint4 (2/thread) ----
  {
    uint4* gdst = (uint4*)(delta + ((size_t)(b * 4096 + t0)) * 256);
#pragma unroll
    for (int k = 0; k < 2; ++k) {
      const int idx = k * 256 + tid;
      gdst[idx] = *(const uint4*)&ld_delta[idx >> 5][(idx & 31) * 8];
    }
  }
  // ---- bc out ----
  if (tid < 128) {
    int row = tid >> 3, q = (tid & 7) * 4;
    float4 v = make_float4(ld_bc[row][q], ld_bc[row][q + 1],
                           ld_bc[row][q + 2], ld_bc[row][q + 3]);
    *(float4*)&bc[((size_t)(b * 4096 + t0 + row)) * 32 + q] = v;
  }
}

// =============== K5b1: within-group combine (in-place exclusive prefix) ===============
// Writes group TOTALS to Gs/Gd (k5b2 scans them) + exclusive dsum prefix dpref.
// S_excl/dpref stored only for EVEN chunks -- k56 replays 32-token windows and
// reads only even-chunk state (odd stores were dead traffic).
__global__ __launch_bounds__(256) void k5b1_group(
    float* __restrict__ S0, float* __restrict__ S1,
    const float* __restrict__ dsum, const float* __restrict__ a2tab,
    float* __restrict__ Gs, float* __restrict__ Gd,
    float* __restrict__ dpref) {
  const int d = threadIdx.x;
  const int n = blockIdx.x & 15, g = (blockIdx.x >> 4) & (NG - 1),
            b = blockIdx.x >> 8;
  float* S = (b & 2) ? (S1 + (size_t)(b & 1) * 1048576)
                     : (S0 + (size_t)(b & 1) * 1048576);
  const float A2 = a2tab[d * 16 + n];
  const size_t s0 = ((size_t)(g * GSZ) * 16 + n) * 256 + d;
  const size_t d0 = ((size_t)b * NCH + g * GSZ) * 256 + d;
  float sv[GSZ], dv[GSZ];
#pragma unroll
  for (int k = 0; k < GSZ; ++k) {
    sv[k] = S[s0 + (size_t)k * 4096];   // chunk stride in S = 16*256
    dv[k] = dsum[d0 + (size_t)k * 256];
  }
  float h = 0.f, cum = 0.f;
#pragma unroll
  for (int k = 0; k < GSZ; ++k) {
    if (!(k & 1)) {                     // only even chunks are consumed
      S[s0 + (size_t)k * 4096] = h;
      if (n == 0) dpref[d0 + (size_t)k * 256] = cum;
    }
    h = fmaf(exp2f(A2 * dv[k]), h, sv[k]);
    cum += dv[k];
  }
  Gs[((size_t)(b * NG + g) * 16 + n) * 256 + d] = h;
  if (n == 0) Gd[((size_t)b * NG + g) * 256 + d] = cum;
}

// =============== K5b2: scan group totals -> exclusive group init, in-place ===============
__global__ __launch_bounds__(256) void k5b2_groupscan(
    float* __restrict__ Gs, const float* __restrict__ Gd,
    const float* __restrict__ a2tab) {
  const int d = threadIdx.x;
  const int n = blockIdx.x & 15, b = blockIdx.x >> 4;
  const float A2 = a2tab[d * 16 + n];
  float sv[NG], dv[NG];
  const size_t g0 = ((size_t)(b * NG) * 16 + n) * 256 + d;
  const size_t gd0 = (size_t)b * NG * 256 + d;
#pragma unroll
  for (int g = 0; g < NG; ++g) {
    sv[g] = Gs[g0 + (size_t)g * 4096];
    dv[g] = Gd[gd0 + (size_t)g * 256];
  }
  float h = 0.f;
#pragma unroll
  for (int g = 0; g < NG; ++g) {
    Gs[g0 + (size_t)g * 4096] = h;
    h = fmaf(exp2f(A2 * dv[g]), h, sv[g]);
  }
}

// =============== K56: replay (2 chunks/block) + activation + out_proj ===============
__global__ __launch_bounds__(256) void k56_fused(
    const unsigned short* __restrict__ xinbf, const float* __restrict__ bc,
    const unsigned short* __restrict__ delta, const unsigned short* __restrict__ z,
    const float* __restrict__ a2tab, const float* __restrict__ Dp,
    const float* __restrict__ dpref, const float* __restrict__ Gs,
    const float* __restrict__ S0, const float* __restrict__ S1,
    const unsigned short* __restrict__ outwbf, const unsigned short* __restrict__ ydsr,
    float* __restrict__ out) {
  __shared__ __align__(16) float bct[32 * 32];
  __shared__ __align__(16) unsigned short sdd[32][264];
  __shared__ __align__(16) unsigned short sdx[32][264];
  __shared__ __align__(16) unsigned short sdz[32][264];   // z, then y
  __shared__ float ldo[16][132];
  const int tid = threadIdx.x;
  const int d = tid;
  const int cp = blockIdx.x & 127, b = blockIdx.x >> 7;
  const int c0 = cp * 2;
  const int t0 = cp * 32;
  const size_t gbase = (size_t)(b * 4096 + t0) * 256;

  // ---- stage streams: 32x256 bf16 per stream = 1024 uint4, 4/thread ----
  {
    const uint4* gd = (const uint4*)(delta + gbase);
    const uint4* gx = (const uint4*)(xinbf + gbase);
    const uint4* gz = (const uint4*)(z + gbase);
#pragma unroll
    for (int k = 0; k < 4; ++k) {
      const int idx = k * 256 + tid;            // 0..1023
      const int row = idx >> 5, c4 = idx & 31;  // 32 uint4 per row
      uint4 vd = gd[idx];
      uint4 vx = gx[idx];
      uint4 vz = gz[idx];
      *(uint4*)&sdd[row][c4 * 8] = vd;
      *(uint4*)&sdx[row][c4 * 8] = vx;
      *(uint4*)&sdz[row][c4 * 8] = vz;
    }
    const float* srcbc = bc + (size_t)(b * 4096 + t0) * 32;
#pragma unroll
    for (int k = 0; k < 4; ++k) bct[k * 256 + tid] = srcbc[k * 256 + tid];
  }

  // ---- per-thread constants + O(1) init ----
  float A2[16];
#pragma unroll
  for (int j = 0; j < 4; ++j) {
    float4 a = *(const float4*)&a2tab[d * 16 + j * 4];
    A2[4 * j + 0] = a.x; A2[4 * j + 1] = a.y;
    A2[4 * j + 2] = a.z; A2[4 * j + 3] = a.w;
  }
  const float Dpd = Dp[d];
  const int g = c0 >> 4;
  const float dp0 = dpref[((size_t)b * NCH + c0) * 256 + d];
  const float* S = (b & 2) ? (S1 + (size_t)(b & 1) * 1048576)
                           : (S0 + (size_t)(b & 1) * 1048576);
  const size_t sbase = ((size_t)c0 * 16) * 256 + d;
  const size_t gsb = ((size_t)(b * NG + g) * 16) * 256 + d;
  float h[16];
#pragma unroll
  for (int n = 0; n < 16; ++n) {
    float gi = Gs[gsb + (size_t)n * 256];     // exclusive group init
    float hl = S[sbase + (size_t)n * 256];    // exclusive chunk-local state
    h[n] = fmaf(exp2f(A2[n] * dp0), gi, hl);
  }
  __syncthreads();

  // ---- replay 32 steps from LDS ----
#pragma unroll
  for (int i = 0; i < 32; ++i) {
    float dl = bf2f(sdd[i][d]);
    float xv = bf2f(sdx[i][d]);
    float zv = bf2f(sdz[i][d]);
    float dlx = dl * xv;
    const float* r = &bct[i * 32];
    float y = 0.f;
#pragma unroll
    for (int n = 0; n < 16; ++n) {
      h[n] = fmaf(exp2f(dl * A2[n]), h[n], dlx * r[n]);
      y = fmaf(h[n], r[16 + n], y);
    }
    sdz[i][d] = f2bf((y + xv * Dpd) * fast_silu(zv));   // overwrite z with y
  }
  __syncthreads();

  // ---- phase B: out_proj MFMA + residual, 2 t-tiles ----
  const int lane = tid & 63;
  const int w = tid >> 6;
  const int col = lane & 15, quad = lane >> 4;
  const int oy = t0 >> 6, ox0 = t0 & 63;
#pragma unroll
  for (int tt = 0; tt < 2; ++tt) {
    bh8 afrag[8];
#pragma unroll
    for (int kb = 0; kb < 8; ++kb)
      afrag[kb] = *(const bh8*)&sdz[tt * 16 + col][quad * 8 + kb * 32];
    f4v acc[2];
#pragma unroll
    for (int j = 0; j < 2; ++j) acc[j] = (f4v){0.f, 0.f, 0.f, 0.f};
    const int nt0 = w * 2;
    const unsigned short* wb = outwbf + (size_t)(nt0 * 16 + col) * 256 + quad * 8;
#pragma unroll
    for (int kb = 0; kb < 8; ++kb) {
#pragma unroll
      for (int j = 0; j < 2; ++j) {
        bh8 bfrag = *(const bh8*)&wb[(size_t)j * 4096 + kb * 32];
        acc[j] = __builtin_amdgcn_mfma_f32_16x16x32_bf16(afrag[kb], bfrag, acc[j], 0, 0, 0);
      }
    }
#pragma unroll
    for (int j = 0; j < 2; ++j)
#pragma unroll
      for (int r = 0; r < 4; ++r)
        ldo[quad * 4 + r][(nt0 + j) * 16 + col] = acc[j][r];
    __syncthreads();
    {
      const int cc = tid >> 1, half = tid & 1;
      size_t obase = (((size_t)(b * 128 + cc) * 64) + oy) * 64 + ox0 + tt * 16 + half * 8;
      const unsigned short* rp = ydsr + obase;
      const int m0 = half * 8;
      float4 o0 = make_float4(ldo[m0 + 0][cc] + bf2f(rp[0]), ldo[m0 + 1][cc] + bf2f(rp[1]),
                              ldo[m0 + 2][cc] + bf2f(rp[2]), ldo[m0 + 3][cc] + bf2f(rp[3]));
      float4 o1 = make_float4(ldo[m0 + 4][cc] + bf2f(rp[4]), ldo[m0 + 5][cc] + bf2f(rp[5]),
                              ldo[m0 + 6][cc] + bf2f(rp[6]), ldo[m0 + 7][cc] + bf2f(rp[7]));
      *(float4*)&out[obase] = o0;
      *(float4*)&out[obase + 4] = o1;
    }
    __syncthreads();   // ldo reused by next tile
  }
}

// =============== launch ===============
extern "C" void kernel_launch(void* const* d_in, const int* in_sizes, int n_in,
                              void* d_out, int out_size, void* d_ws, size_t ws_size,
                              hipStream_t stream) {
  (void)in_sizes; (void)n_in; (void)out_size; (void)ws_size;
  const float* x        = (const float*)d_in[0];
  const float* conv_w   = (const float*)d_in[1];
  const float* conv_b   = (const float*)d_in[2];
  const float* bn_g     = (const float*)d_in[3];
  const float* bn_b     = (const float*)d_in[4];
  const float* bn_mean  = (const float*)d_in[5];
  const float* bn_var   = (const float*)d_in[6];
  const float* in_w     = (const float*)d_in[7];
  const float* conv1d_w = (const float*)d_in[8];
  const float* conv1d_b = (const float*)d_in[9];
  const float* xproj_w  = (const float*)d_in[10];
  const float* dtproj_w = (const float*)d_in[11];
  const float* dtproj_b = (const float*)d_in[12];
  const float* A_log    = (const float*)d_in[13];
  const float* Dp       = (const float*)d_in[14];
  const float* out_w    = (const float*)d_in[15];
  float* ws = (float*)d_ws;
  float* out = (float*)d_out;

  k0x_prep<<<2033, 256, 0, stream>>>(conv_w, conv_b, bn_g, bn_b, bn_mean, bn_var,
                                     xproj_w, A_log, dtproj_w, in_w, out_w, x, ws);
  k12_conv_inproj<<<512, 512, 0, stream>>>(
      (const unsigned short*)(ws + OFF_XT),
      (const unsigned short*)(ws + OFF_WBF), ws + OFF_BIAS2,
      (const unsigned short*)(ws + OFF_INWBF),
      (unsigned short*)(ws + OFF_YDSR),
      (unsigned short*)(ws + OFF_XPRE),
      (unsigned short*)(ws + OFF_Z));
  k45_mfma<<<1024, 256, 0, stream>>>((const unsigned short*)(ws + OFF_WCMP),
                                     dtproj_b,
                                     (const unsigned short*)(ws + OFF_XPRE),
                                     conv1d_w, conv1d_b, ws + OFF_A2,
                                     (unsigned short*)(ws + OFF_XT),
                                     (unsigned short*)(ws + OFF_DELTA),
                                     ws + OFF_BC, ws + OFF_DSUM,
                                     ws + OFF_S0, ws + OFF_S1);
  k5b1_group<<<1024, 256, 0, stream>>>(ws + OFF_S0, ws + OFF_S1, ws + OFF_DSUM,
                                       ws + OFF_A2, ws + OFF_GS, ws + OFF_GD,
                                       ws + OFF_DPREF);
  k5b2_groupscan<<<64, 256, 0, stream>>>(ws + OFF_GS, ws + OFF_GD, ws + OFF_A2);
  k56_fused<<<512, 256, 0, stream>>>((const unsigned short*)(ws + OFF_XT),
                                     ws + OFF_BC,
                                     (const unsigned short*)(ws + OFF_DELTA),
                                     (const unsigned short*)(ws + OFF_Z),
                                     ws + OFF_A2, Dp, ws + OFF_DPREF,
                                     ws + OFF_GS,
                                     ws + OFF_S0, ws + OFF_S1,
                                     (const unsigned short*)(ws + OFF_OUTWBF),
                                     (const unsigned short*)(ws + OFF_YDSR), out);
}

// Round 12
// 206.010 us; speedup vs baseline: 1.0825x; 1.0825x over previous
//
#include <hip/hip_runtime.h>
#include <math.h>

// ---------------- problem sizes ----------------
#define NB 4
#define LTOK 4096
#define DM 128
#define DI 256
#define NCH 256    // scan chunks
#define TCH 16     // steps per chunk
#define GSZ 16     // chunks per combine group
#define NG  16     // groups = NCH/GSZ

// ---------------- workspace layout (float offsets) ----------------
#define OFF_A2     0u          // A2 table [256d][16n] (4096)
#define OFF_BIAS2  73728u      // folded conv+bn bias [128]
#define OFF_YDSR   84096u      // bf16 gelu NCHW [4][128][64][64] (1048576 fl)
#define OFF_XPRE   2181248u    // bf16 xpre [4][4096][256] (2097152 fl)
#define OFF_S0     4278400u    // f32 S slices b=0,1 [2][256c][16n][256d] (2097152 fl)
#define OFF_Z      6375552u    // bf16 z [4][4096][256] (2097152 fl)
#define OFF_DELTA  10569856u   // bf16 delta [4][4096][256] (2097152 fl)
#define OFF_S1     12667008u   // f32 S slices b=2,3 (2097152 fl)
#define OFF_BC     14764160u   // f32 [4][4096][32]: 0-15 B, 16-31 C (524288)
#define OFF_DSUM   15288448u   // [4][256c][256d] (262144)
#define OFF_GS     15550592u   // [4][16g][16n][256d] group totals -> excl prefix (262144)
#define OFF_GD     15812736u   // [4][16g][256d] group dsum totals (16384)
#define OFF_XT     15829120u   // bf16: x-transpose (k0x/k12); then xinbf [4][4096][256]
#define OFF_WBF    17926272u   // bf16 conv weights*bn_inv [128co][9tap][64ci] (36864)
#define OFF_WCMP   17963136u   // bf16 composed xproj weights [320n][256k] (40960)
#define OFF_DPREF  18004096u   // f32 exclusive dsum prefix [4][256c][256d] (262144)
#define OFF_INWBF  19052672u   // bf16 in_w [512e][128k] (32768)
#define OFF_OUTWBF 19085440u   // bf16 out_w [128cc][256e] (16384)
// total 19101824 floats = 76.4 MB

#define DEV __device__ __forceinline__
#define L2E 1.4426950408889634f

typedef short bh8 __attribute__((ext_vector_type(8)));   // 8 bf16 (4 VGPR)
typedef float f4v __attribute__((ext_vector_type(4)));

DEV float fast_silu(float v) {
  return v * __builtin_amdgcn_rcpf(1.f + __expf(-v));
}

DEV unsigned short f2bf(float f) {                       // round-to-nearest-even
  unsigned int u = __float_as_uint(f);
  u = (u + 0x7FFFu + ((u >> 16) & 1u)) >> 16;
  return (unsigned short)u;
}

DEV float bf2f(unsigned short us) {
  return __uint_as_float((unsigned int)us << 16);
}

// =============== K0x: weight prep + x transpose (merged) ===============
__global__ __launch_bounds__(256) void k0x_prep(
    const float* __restrict__ conv_w, const float* __restrict__ conv_b,
    const float* __restrict__ bn_g, const float* __restrict__ bn_b,
    const float* __restrict__ bn_mean, const float* __restrict__ bn_var,
    const float* __restrict__ xproj_w, const float* __restrict__ A_log,
    const float* __restrict__ dtw, const float* __restrict__ in_w,
    const float* __restrict__ out_w, const float* __restrict__ x,
    float* __restrict__ ws) {
  __shared__ float t[64][65];
  if (blockIdx.x >= 1009) {
    // ---- transpose part: x [4][64][128][128] f32 -> xt [4][128][128][64] bf16
    const int bid = blockIdx.x - 1009;
    unsigned short* xt = (unsigned short*)(ws + OFF_XT);
    const int tid = threadIdx.x;
    const int ixh = bid & 1;
    const int iy = (bid >> 1) & 127;
    const int b = bid >> 8;
    {
      const int ixl = tid & 63, cw = tid >> 6;
#pragma unroll 4
      for (int i = 0; i < 16; ++i) {
        int ci = cw * 16 + i;
        t[ci][ixl] = x[(((size_t)(b * 64 + ci) * 128) + iy) * 128 + ixh * 64 + ixl];
      }
    }
    __syncthreads();
    {
      const int cil = tid & 63, iw = tid >> 6;
      unsigned short* dst = xt + (((size_t)(b * 128 + iy) * 128) + ixh * 64) * 64;
#pragma unroll 4
      for (int i = 0; i < 16; ++i) {
        int ix = iw * 16 + i;
        dst[ix * 64 + cil] = f2bf(t[cil][ix]);
      }
    }
    return;
  }
  // ---- prep part ----
  int i = blockIdx.x * 256 + threadIdx.x;
  if (i < 73728) {
    int ci = i & 63; int tap = (i >> 6) % 9; int co = i / 576;
    float inv = bn_g[co] * rsqrtf(bn_var[co] + 1e-5f);
    ((unsigned short*)(ws + OFF_WBF))[i] = f2bf(conv_w[co * 576 + ci * 9 + tap] * inv);
  } else if (i < 73856) {
    int co = i - 73728;
    float inv = bn_g[co] * rsqrtf(bn_var[co] + 1e-5f);
    ws[OFF_BIAS2 + co] = (conv_b[co] - bn_mean[co]) * inv + bn_b[co];
  } else if (i < 77952) {
    int j = i - 73856;
    ws[OFF_A2 + j] = -__expf(A_log[j]) * L2E;
  } else if (i < 159872) {
    // wcomp[n][k], n in [0,320)
    int j = i - 77952;
    int n = j >> 8, k = j & 255;
    float v = 0.f;
    if (n < 256) {
#pragma unroll
      for (int r = 0; r < 8; ++r)
        v = fmaf(dtw[n * 8 + r], xproj_w[r * 256 + k], v);
    } else if (n < 288) {
      v = xproj_w[(8 + n - 256) * 256 + k];
    }
    ((unsigned short*)(ws + OFF_WCMP))[j] = f2bf(v);
  } else if (i < 225408) {
    int j = i - 159872;                                  // [512e][128k]
    ((unsigned short*)(ws + OFF_INWBF))[j] = f2bf(in_w[j]);
  } else if (i < 258176) {
    int j = i - 225408;                                  // [128cc][256e]
    ((unsigned short*)(ws + OFF_OUTWBF))[j] = f2bf(out_w[j]);
  }
}

// =============== K12: conv3x3 s2 + BN + GELU + in_proj (fused) ===============
__global__ __launch_bounds__(512) void k12_conv_inproj(
    const unsigned short* __restrict__ xt, const unsigned short* __restrict__ wbf,
    const float* __restrict__ bias2, const unsigned short* __restrict__ inwbf,
    unsigned short* __restrict__ ydsr, unsigned short* __restrict__ xpre,
    unsigned short* __restrict__ z) {
  __shared__ unsigned short ldt[64][136];
  const int tid = threadIdx.x;
  const int lane = tid & 63;
  const int w = tid >> 6;                 // 0..7
  const int col = lane & 15, quad = lane >> 4;
  const int oy = blockIdx.x & 63;
  const int b = blockIdx.x >> 6;
  const int co_w = w * 16;
  const int iy0 = 2 * oy - 1;
  const bh8 bzero = {};

  // ---- conv phase ----
  f4v acc[4];
#pragma unroll
  for (int nt = 0; nt < 4; ++nt) acc[nt] = (f4v){0.f, 0.f, 0.f, 0.f};
  const unsigned short* ap = wbf + (size_t)(co_w + col) * 576;
  for (int tap = 0; tap < 9; ++tap) {
    const int kh = tap / 3, kw = tap - kh * 3;
    const int iy = iy0 + kh;
    const unsigned short* xrow = xt + (long)(b * 128 + iy) * 8192;
    const bool oky = (iy >= 0);
#pragma unroll
    for (int kc = 0; kc < 2; ++kc) {
      const int cib = kc * 32 + quad * 8;
      bh8 a0 = *(const bh8*)&ap[tap * 64 + cib];
#pragma unroll
      for (int nt = 0; nt < 4; ++nt) {
        const int ix = 2 * (nt * 16 + col) - 1 + kw;
        bh8 bv = *(const bh8*)&xrow[(long)ix * 64 + cib];
        if (!(oky && ix >= 0)) bv = bzero;
        acc[nt] = __builtin_amdgcn_mfma_f32_16x16x32_bf16(a0, bv, acc[nt], 0, 0, 0);
      }
    }
  }
#pragma unroll
  for (int nt = 0; nt < 4; ++nt) {
    const int tok = nt * 16 + col;
    const int swz = (tok & 15) << 3;
#pragma unroll
    for (int r = 0; r < 4; ++r) {
      const int co = co_w + quad * 4 + r;
      float v = acc[nt][r] + bias2[co];
      float g = 0.5f * v * (1.f + erff(v * 0.70710678118f));
      unsigned short gb = f2bf(g);
      ydsr[(((size_t)(b * 128 + co) * 64) + oy) * 64 + tok] = gb;
      ldt[tok][co ^ swz] = gb;
    }
  }
  __syncthreads();

  // ---- in_proj phase: u[64t][128k] (LDS) x in_w[512e][128k] ----
  const size_t tglob0 = (size_t)(b * 4096 + oy * 64);
#pragma unroll
  for (int tt = 0; tt < 4; ++tt) {
    const int row = tt * 16 + col;
    const int swz = (row & 15) << 3;
    bh8 afrag[4];
#pragma unroll
    for (int kb = 0; kb < 4; ++kb)
      afrag[kb] = *(const bh8*)&ldt[row][(quad * 8 + kb * 32) ^ swz];
    f4v acc2[4];
#pragma unroll
    for (int j = 0; j < 4; ++j) acc2[j] = (f4v){0.f, 0.f, 0.f, 0.f};
#pragma unroll
    for (int kb = 0; kb < 4; ++kb) {
#pragma unroll
      for (int j = 0; j < 4; ++j) {
        const int e_row = (w * 4 + j) * 16 + col;
        bh8 bfrag = *(const bh8*)&inwbf[(size_t)e_row * 128 + quad * 8 + kb * 32];
        acc2[j] = __builtin_amdgcn_mfma_f32_16x16x32_bf16(afrag[kb], bfrag, acc2[j], 0, 0, 0);
      }
    }
#pragma unroll
    for (int j = 0; j < 4; ++j) {
      const int e = (w * 4 + j) * 16 + col;
#pragma unroll
      for (int r = 0; r < 4; ++r) {
        const size_t t = tglob0 + tt * 16 + quad * 4 + r;
        if (e < 256) xpre[t * 256 + e] = f2bf(acc2[j][r]);
        else z[t * 256 + e - 256] = f2bf(acc2[j][r]);
      }
    }
  }
}

// =============== K45: conv1d+SiLU + composed proj MFMA + chunk-local scan ===============
__global__ __launch_bounds__(256) void k45_mfma(
    const unsigned short* __restrict__ wcomp, const float* __restrict__ dtb,
    const unsigned short* __restrict__ xpre, const float* __restrict__ cw1,
    const float* __restrict__ cb1, const float* __restrict__ a2tab,
    unsigned short* __restrict__ xinbf, unsigned short* __restrict__ delta,
    float* __restrict__ bc, float* __restrict__ dsum,
    float* __restrict__ S0, float* __restrict__ S1) {
  __shared__ unsigned short ld_xin[16][264];
  __shared__ unsigned short ld_delta[16][264];
  __shared__ float ld_bc[16][33];
  const int tid = threadIdx.x;
  const int lane = tid & 63;
  const int w = tid >> 6;
  const int col = lane & 15, quad = lane >> 4;
  const int tt = blockIdx.x & 255, b = blockIdx.x >> 8;
  const int t0 = tt * 16;

  // ---- phase 1: conv1d + silu (thread = d) ----
  {
    const int d = tid;
    float4 w4 = *(const float4*)&cw1[d * 4];
    float bias = cb1[d];
    float xw[19];
    const unsigned short* xp = xpre + ((size_t)(b * 4096 + t0 - 3)) * 256 + d;
    if (tt > 0) {
      // uniform branch: all 19 taps in-range -> plain hoistable loads
#pragma unroll
      for (int i = 0; i < 19; ++i) xw[i] = bf2f(xp[(size_t)i * 256]);
    } else {
#pragma unroll
      for (int i = 0; i < 19; ++i) {
        int t = t0 - 3 + i;
        xw[i] = (t >= 0) ? bf2f(xp[(size_t)i * 256]) : 0.f;
      }
    }
    unsigned short* dst = xinbf + ((size_t)(b * 4096 + t0)) * 256 + d;
#pragma unroll
    for (int i = 0; i < 16; ++i) {
      float o = bias + w4.x * xw[i] + w4.y * xw[i + 1] + w4.z * xw[i + 2] +
                w4.w * xw[i + 3];
      unsigned short us = f2bf(fast_silu(o));
      ld_xin[i][d] = us;
      dst[(size_t)i * 256] = us;
    }
  }
  __syncthreads();

  // ---- phase 2: MFMA ----
  {
    bh8 afrag[8];
#pragma unroll
    for (int kb = 0; kb < 8; ++kb)
      afrag[kb] = *(const bh8*)&ld_xin[col][quad * 8 + kb * 32];
    f4v acc[5];
#pragma unroll
    for (int j = 0; j < 5; ++j) acc[j] = (f4v){0.f, 0.f, 0.f, 0.f};

    const int nt0 = w * 5;
    const unsigned short* wb = wcomp + (size_t)(nt0 * 16 + col) * 256 + quad * 8;
#pragma unroll
    for (int kb = 0; kb < 8; ++kb) {
#pragma unroll
      for (int j = 0; j < 5; ++j) {
        bh8 bfrag = *(const bh8*)&wb[(size_t)j * 4096 + kb * 32];
        acc[j] = __builtin_amdgcn_mfma_f32_16x16x32_bf16(afrag[kb], bfrag, acc[j], 0, 0, 0);
      }
    }
#pragma unroll
    for (int j = 0; j < 5; ++j) {
      const int n = (nt0 + j) * 16 + col;
      if (n < 256) {
        float bias = dtb[n];
#pragma unroll
        for (int r = 0; r < 4; ++r) {
          float s = acc[j][r] + bias;
          float dl = fmaxf(s, 0.f) + __logf(1.f + __expf(-fabsf(s)));  // softplus
          ld_delta[quad * 4 + r][n] = f2bf(dl);
        }
      } else if (n < 288) {
#pragma unroll
        for (int r = 0; r < 4; ++r) ld_bc[quad * 4 + r][n - 256] = acc[j][r];
      }
    }
  }
  __syncthreads();

  // ---- phase 3: chunk-local scan from LDS (thread = d) ----
  {
    const int d = tid;
    float A2[16];
#pragma unroll
    for (int j = 0; j < 4; ++j) {
      float4 a = *(const float4*)&a2tab[d * 16 + j * 4];
      A2[4 * j + 0] = a.x; A2[4 * j + 1] = a.y;
      A2[4 * j + 2] = a.z; A2[4 * j + 3] = a.w;
    }
    float h[16];
#pragma unroll
    for (int n = 0; n < 16; ++n) h[n] = 0.f;
    float ds = 0.f;
#pragma unroll 4
    for (int i = 0; i < TCH; ++i) {
      float dl = bf2f(ld_delta[i][d]);
      float xv = bf2f(ld_xin[i][d]);
      ds += dl;
      float dlx = dl * xv;
#pragma unroll
      for (int n = 0; n < 16; ++n)
        h[n] = fmaf(exp2f(dl * A2[n]), h[n], dlx * ld_bc[i][n]);
    }
    dsum[((size_t)b * NCH + tt) * 256 + d] = ds;
    float* S = (b & 2) ? (S1 + (size_t)(b & 1) * 1048576)
                       : (S0 + (size_t)(b & 1) * 1048576);
    const size_t sbase = ((size_t)tt * 16) * 256 + d;
#pragma unroll
    for (int n = 0; n < 16; ++n) S[sbase + (size_t)n * 256] = h[n];
  }

  // ---- outputs for the replay kernel ----
#pragma unroll
  for (int it = 0; it < 4; ++it) {
    int idx = it * 256 + tid;
    int row = idx >> 6, d4 = (idx & 63) * 4;
    unsigned long long pk = *(const unsigned long long*)&ld_delta[row][d4];
    *(unsigned long long*)&delta[((size_t)(b * 4096 + t0 + row)) * 256 + d4] = pk;
  }
  // ---- bc out ----
  if (tid < 128) {
    int row = tid >> 3, q = (tid & 7) * 4;
    float4 v = make_float4(ld_bc[row][q], ld_bc[row][q + 1],
                           ld_bc[row][q + 2], ld_bc[row][q + 3]);
    *(float4*)&bc[((size_t)(b * 4096 + t0 + row)) * 32 + q] = v;
  }
}

// =============== K5b1: within-group combine (in-place exclusive prefix) ===============
// Writes group TOTALS to Gs/Gd (k5b2 scans them) + exclusive dsum prefix dpref.
__global__ __launch_bounds__(256) void k5b1_group(
    float* __restrict__ S0, float* __restrict__ S1,
    const float* __restrict__ dsum, const float* __restrict__ a2tab,
    float* __restrict__ Gs, float* __restrict__ Gd,
    float* __restrict__ dpref) {
  const int d = threadIdx.x;
  const int n = blockIdx.x & 15, g = (blockIdx.x >> 4) & (NG - 1),
            b = blockIdx.x >> 8;
  float* S = (b & 2) ? (S1 + (size_t)(b & 1) * 1048576)
                     : (S0 + (size_t)(b & 1) * 1048576);
  const float A2 = a2tab[d * 16 + n];
  const size_t s0 = ((size_t)(g * GSZ) * 16 + n) * 256 + d;
  const size_t d0 = ((size_t)b * NCH + g * GSZ) * 256 + d;
  float sv[GSZ], dv[GSZ];
#pragma unroll
  for (int k = 0; k < GSZ; ++k) {
    sv[k] = S[s0 + (size_t)k * 4096];   // chunk stride in S = 16*256
    dv[k] = dsum[d0 + (size_t)k * 256];
  }
  float h = 0.f, cum = 0.f;
#pragma unroll
  for (int k = 0; k < GSZ; ++k) {
    S[s0 + (size_t)k * 4096] = h;
    if (n == 0) dpref[d0 + (size_t)k * 256] = cum;
    h = fmaf(exp2f(A2 * dv[k]), h, sv[k]);
    cum += dv[k];
  }
  Gs[((size_t)(b * NG + g) * 16 + n) * 256 + d] = h;
  if (n == 0) Gd[((size_t)b * NG + g) * 256 + d] = cum;
}

// =============== K5b2: scan group totals -> exclusive group init, in-place ===============
__global__ __launch_bounds__(256) void k5b2_groupscan(
    float* __restrict__ Gs, const float* __restrict__ Gd,
    const float* __restrict__ a2tab) {
  const int d = threadIdx.x;
  const int n = blockIdx.x & 15, b = blockIdx.x >> 4;
  const float A2 = a2tab[d * 16 + n];
  float sv[NG], dv[NG];
  const size_t g0 = ((size_t)(b * NG) * 16 + n) * 256 + d;
  const size_t gd0 = (size_t)b * NG * 256 + d;
#pragma unroll
  for (int g = 0; g < NG; ++g) {
    sv[g] = Gs[g0 + (size_t)g * 4096];
    dv[g] = Gd[gd0 + (size_t)g * 256];
  }
  float h = 0.f;
#pragma unroll
  for (int g = 0; g < NG; ++g) {
    Gs[g0 + (size_t)g * 4096] = h;
    h = fmaf(exp2f(A2 * dv[g]), h, sv[g]);
  }
}

// =============== K56: replay (2 chunks/block) + activation + out_proj ===============
// Grid 512 = (b, cp); block replays 32 tokens (chunks 2cp, 2cp+1) -- the
// recurrence continues across the chunk boundary, so only S[2cp] is read.
// Streams staged into LDS via uint4 loads (12/thread total). y overwrites the
// z tile in place. Init is O(1) (Gs pre-scanned by k5b2).
__global__ __launch_bounds__(256) void k56_fused(
    const unsigned short* __restrict__ xinbf, const float* __restrict__ bc,
    const unsigned short* __restrict__ delta, const unsigned short* __restrict__ z,
    const float* __restrict__ a2tab, const float* __restrict__ Dp,
    const float* __restrict__ dpref, const float* __restrict__ Gs,
    const float* __restrict__ S0, const float* __restrict__ S1,
    const unsigned short* __restrict__ outwbf, const unsigned short* __restrict__ ydsr,
    float* __restrict__ out) {
  __shared__ __align__(16) float bct[32 * 32];
  __shared__ __align__(16) unsigned short sdd[32][264];
  __shared__ __align__(16) unsigned short sdx[32][264];
  __shared__ __align__(16) unsigned short sdz[32][264];   // z, then y
  __shared__ float ldo[16][132];
  const int tid = threadIdx.x;
  const int d = tid;
  const int cp = blockIdx.x & 127, b = blockIdx.x >> 7;
  const int c0 = cp * 2;
  const int t0 = cp * 32;
  const size_t gbase = (size_t)(b * 4096 + t0) * 256;

  // ---- stage streams: 32x256 bf16 per stream = 1024 uint4, 4/thread ----
  {
    const uint4* gd = (const uint4*)(delta + gbase);
    const uint4* gx = (const uint4*)(xinbf + gbase);
    const uint4* gz = (const uint4*)(z + gbase);
#pragma unroll
    for (int k = 0; k < 4; ++k) {
      const int idx = k * 256 + tid;            // 0..1023
      const int row = idx >> 5, c4 = idx & 31;  // 32 uint4 per row
      uint4 vd = gd[idx];
      uint4 vx = gx[idx];
      uint4 vz = gz[idx];
      *(uint4*)&sdd[row][c4 * 8] = vd;
      *(uint4*)&sdx[row][c4 * 8] = vx;
      *(uint4*)&sdz[row][c4 * 8] = vz;
    }
    const float* srcbc = bc + (size_t)(b * 4096 + t0) * 32;
#pragma unroll
    for (int k = 0; k < 4; ++k) bct[k * 256 + tid] = srcbc[k * 256 + tid];
  }

  // ---- per-thread constants + O(1) init ----
  float A2[16];
#pragma unroll
  for (int j = 0; j < 4; ++j) {
    float4 a = *(const float4*)&a2tab[d * 16 + j * 4];
    A2[4 * j + 0] = a.x; A2[4 * j + 1] = a.y;
    A2[4 * j + 2] = a.z; A2[4 * j + 3] = a.w;
  }
  const float Dpd = Dp[d];
  const int g = c0 >> 4;
  const float dp0 = dpref[((size_t)b * NCH + c0) * 256 + d];
  const float* S = (b & 2) ? (S1 + (size_t)(b & 1) * 1048576)
                           : (S0 + (size_t)(b & 1) * 1048576);
  const size_t sbase = ((size_t)c0 * 16) * 256 + d;
  const size_t gsb = ((size_t)(b * NG + g) * 16) * 256 + d;
  float h[16];
#pragma unroll
  for (int n = 0; n < 16; ++n) {
    float gi = Gs[gsb + (size_t)n * 256];     // exclusive group init
    float hl = S[sbase + (size_t)n * 256];    // exclusive chunk-local state
    h[n] = fmaf(exp2f(A2[n] * dp0), gi, hl);
  }
  __syncthreads();

  // ---- replay 32 steps from LDS ----
#pragma unroll
  for (int i = 0; i < 32; ++i) {
    float dl = bf2f(sdd[i][d]);
    float xv = bf2f(sdx[i][d]);
    float zv = bf2f(sdz[i][d]);
    float dlx = dl * xv;
    const float* r = &bct[i * 32];
    float y = 0.f;
#pragma unroll
    for (int n = 0; n < 16; ++n) {
      h[n] = fmaf(exp2f(dl * A2[n]), h[n], dlx * r[n]);
      y = fmaf(h[n], r[16 + n], y);
    }
    sdz[i][d] = f2bf((y + xv * Dpd) * fast_silu(zv));   // overwrite z with y
  }
  __syncthreads();

  // ---- phase B: out_proj MFMA + residual, 2 t-tiles ----
  const int lane = tid & 63;
  const int w = tid >> 6;
  const int col = lane & 15, quad = lane >> 4;
  const int oy = t0 >> 6, ox0 = t0 & 63;
#pragma unroll
  for (int tt = 0; tt < 2; ++tt) {
    bh8 afrag[8];
#pragma unroll
    for (int kb = 0; kb < 8; ++kb)
      afrag[kb] = *(const bh8*)&sdz[tt * 16 + col][quad * 8 + kb * 32];
    f4v acc[2];
#pragma unroll
    for (int j = 0; j < 2; ++j) acc[j] = (f4v){0.f, 0.f, 0.f, 0.f};
    const int nt0 = w * 2;
    const unsigned short* wb = outwbf + (size_t)(nt0 * 16 + col) * 256 + quad * 8;
#pragma unroll
    for (int kb = 0; kb < 8; ++kb) {
#pragma unroll
      for (int j = 0; j < 2; ++j) {
        bh8 bfrag = *(const bh8*)&wb[(size_t)j * 4096 + kb * 32];
        acc[j] = __builtin_amdgcn_mfma_f32_16x16x32_bf16(afrag[kb], bfrag, acc[j], 0, 0, 0);
      }
    }
#pragma unroll
    for (int j = 0; j < 2; ++j)
#pragma unroll
      for (int r = 0; r < 4; ++r)
        ldo[quad * 4 + r][(nt0 + j) * 16 + col] = acc[j][r];
    __syncthreads();
    {
      const int cc = tid >> 1, half = tid & 1;
      size_t obase = (((size_t)(b * 128 + cc) * 64) + oy) * 64 + ox0 + tt * 16 + half * 8;
      const unsigned short* rp = ydsr + obase;
      const int m0 = half * 8;
      float4 o0 = make_float4(ldo[m0 + 0][cc] + bf2f(rp[0]), ldo[m0 + 1][cc] + bf2f(rp[1]),
                              ldo[m0 + 2][cc] + bf2f(rp[2]), ldo[m0 + 3][cc] + bf2f(rp[3]));
      float4 o1 = make_float4(ldo[m0 + 4][cc] + bf2f(rp[4]), ldo[m0 + 5][cc] + bf2f(rp[5]),
                              ldo[m0 + 6][cc] + bf2f(rp[6]), ldo[m0 + 7][cc] + bf2f(rp[7]));
      *(float4*)&out[obase] = o0;
      *(float4*)&out[obase + 4] = o1;
    }
    __syncthreads();   // ldo reused by next tile
  }
}

// =============== launch ===============
extern "C" void kernel_launch(void* const* d_in, const int* in_sizes, int n_in,
                              void* d_out, int out_size, void* d_ws, size_t ws_size,
                              hipStream_t stream) {
  (void)in_sizes; (void)n_in; (void)out_size; (void)ws_size;
  const float* x        = (const float*)d_in[0];
  const float* conv_w   = (const float*)d_in[1];
  const float* conv_b   = (const float*)d_in[2];
  const float* bn_g     = (const float*)d_in[3];
  const float* bn_b     = (const float*)d_in[4];
  const float* bn_mean  = (const float*)d_in[5];
  const float* bn_var   = (const float*)d_in[6];
  const float* in_w     = (const float*)d_in[7];
  const float* conv1d_w = (const float*)d_in[8];
  const float* conv1d_b = (const float*)d_in[9];
  const float* xproj_w  = (const float*)d_in[10];
  const float* dtproj_w = (const float*)d_in[11];
  const float* dtproj_b = (const float*)d_in[12];
  const float* A_log    = (const float*)d_in[13];
  const float* Dp       = (const float*)d_in[14];
  const float* out_w    = (const float*)d_in[15];
  float* ws = (float*)d_ws;
  float* out = (float*)d_out;

  k0x_prep<<<2033, 256, 0, stream>>>(conv_w, conv_b, bn_g, bn_b, bn_mean, bn_var,
                                     xproj_w, A_log, dtproj_w, in_w, out_w, x, ws);
  k12_conv_inproj<<<256, 512, 0, stream>>>(
      (const unsigned short*)(ws + OFF_XT),
      (const unsigned short*)(ws + OFF_WBF), ws + OFF_BIAS2,
      (const unsigned short*)(ws + OFF_INWBF),
      (unsigned short*)(ws + OFF_YDSR),
      (unsigned short*)(ws + OFF_XPRE),
      (unsigned short*)(ws + OFF_Z));
  k45_mfma<<<1024, 256, 0, stream>>>((const unsigned short*)(ws + OFF_WCMP),
                                     dtproj_b,
                                     (const unsigned short*)(ws + OFF_XPRE),
                                     conv1d_w, conv1d_b, ws + OFF_A2,
                                     (unsigned short*)(ws + OFF_XT),
                                     (unsigned short*)(ws + OFF_DELTA),
                                     ws + OFF_BC, ws + OFF_DSUM,
                                     ws + OFF_S0, ws + OFF_S1);
  k5b1_group<<<1024, 256, 0, stream>>>(ws + OFF_S0, ws + OFF_S1, ws + OFF_DSUM,
                                       ws + OFF_A2, ws + OFF_GS, ws + OFF_GD,
                                       ws + OFF_DPREF);
  k5b2_groupscan<<<64, 256, 0, stream>>>(ws + OFF_GS, ws + OFF_GD, ws + OFF_A2);
  k56_fused<<<512, 256, 0, stream>>>((const unsigned short*)(ws + OFF_XT),
                                     ws + OFF_BC,
                                     (const unsigned short*)(ws + OFF_DELTA),
                                     (const unsigned short*)(ws + OFF_Z),
                                     ws + OFF_A2, Dp, ws + OFF_DPREF,
                                     ws + OFF_GS,
                                     ws + OFF_S0, ws + OFF_S1,
                                     (const unsigned short*)(ws + OFF_OUTWBF),
                                     (const unsigned short*)(ws + OFF_YDSR), out);
}